// Round 3
// baseline (664.725 us; speedup 1.0000x reference)
//
#include <hip/hip_runtime.h>

// Q4_0 quantized linear: out[16, 11008] = x[16, 4096] @ ((w_q-8)*w_scale).T + bias
// All fp32; w_q holds int32 nibble values in [0,16).
//
// R=2 row-blocked split-K GEMV, CK=64 (64 k-splits), OCCUPANCY-PINNED.
// History:
//  R0 baseline (R=4, CK=128, 352 blocks): 110 us, VGPR 84, occupancy 15%,
//     latency-bound (both pipes idle, 1.375 blocks/CU).
//  R1 (reg-prefetch): VGPR 256 + scratch spill storm, 1540 us. Reverted.
//  R2 (R=2, CK=64, 1408 blocks, no launch hint): compiler ran to the
//     256-VGPR cap on its own -> 2 waves/SIMD ceiling, occupancy 10%,
//     168 us. The grid fix never became resident parallelism.
//  R3 (this): __launch_bounds__(256, 4) pins VGPR <= 128 (structure needs
//     ~84, proven in R0) -> 4 blocks/CU resident, 5.5 blocks/CU in grid.
//     Cross-block TLP covers the barrier-fenced staging phases.
// Structure unchanged: w packed to BYTES in LDS (row stride 36 B -> 2-way
// bank aliasing = free), x chunk staged transposed for broadcast float4
// reads, fp32 atomicAdd split-K combine, bias added by split 0.

constexpr int T       = 16;
constexpr int IN      = 4096;
constexpr int OUT     = 11008;
constexpr int NSCALE  = IN / 32;        // 128 scales per row
constexpr int THREADS = 256;
constexpr int R       = 2;              // rows per thread
constexpr int ROWSB   = THREADS * R;    // 512 rows per block
constexpr int CK      = 64;             // k per block (split-K chunk)
constexpr int WSUB    = 32;             // k per stage (== Q4_0 block size)
constexpr int NSUB    = CK / WSUB;      // 2
constexpr int WSTRIDE = 36;             // ws8 row stride bytes (32 + 4 pad -> 9 words)
constexpr int XPAD    = 20;             // xs row stride floats (80 B, 16B-aligned)

__global__ __launch_bounds__(THREADS, 4) void qlinear_r2k64o(
    const float* __restrict__ x,        // [T, IN]
    const int*   __restrict__ w_q,      // [OUT, IN]
    const float* __restrict__ w_scale,  // [OUT, NSCALE]
    const float* __restrict__ bias,     // [OUT]
    float* __restrict__ out)            // [T, OUT] (pre-zeroed)
{
    __shared__ __align__(16) float         xs[CK][XPAD];         // 5.0 KiB
    __shared__ __align__(16) unsigned char ws8[ROWSB * WSTRIDE]; // 18.0 KiB

    const int tid  = threadIdx.x;
    const int row0 = blockIdx.x * ROWSB;
    const int k0   = blockIdx.y * CK;

    // ---- stage x chunk transposed: xs[k][t] = x[t][k0+k] (coalesced) ----
    #pragma unroll
    for (int it = 0; it < CK * T / THREADS; ++it) {  // 4
        int idx = it * THREADS + tid;
        int t   = idx >> 6;          // idx / CK
        int k   = idx & (CK - 1);
        xs[k][t] = x[t * IN + k0 + k];
    }

    // ---- per-row scales for the 2 sub-blocks of this k-chunk ----
    float2 sc[R];
    #pragma unroll
    for (int r = 0; r < R; ++r) {
        int rg = min(row0 + tid + r * THREADS, OUT - 1);
        sc[r] = *(const float2*)(w_scale + rg * NSCALE + (k0 >> 5));
    }

    float acc[R][T];
    #pragma unroll
    for (int r = 0; r < R; ++r)
        #pragma unroll
        for (int t = 0; t < T; ++t) acc[r][t] = 0.0f;

    #pragma unroll
    for (int sub = 0; sub < NSUB; ++sub) {           // 2
        __syncthreads();   // protect ws8 reuse (covers xs on first trip)

        // ---- stage w tile: 512 rows x 32 ints -> packed bytes in LDS ----
        // flat int4 id f: row rr = f/8, j = f%8; lanes 0..7 read 128
        // contiguous bytes of one row (fully coalesced dwordx4 loads).
        #pragma unroll 4
        for (int it = 0; it < (ROWSB * WSUB / 4) / THREADS; ++it) {  // 16
            int f  = it * THREADS + tid;
            int rr = f >> 3;
            int j  = f & 7;
            int rg = min(row0 + rr, OUT - 1);
            const int4 v = *(const int4*)(w_q + rg * IN + k0 + sub * WSUB + j * 4);
            unsigned int u = (unsigned)v.x | ((unsigned)v.y << 8) |
                             ((unsigned)v.z << 16) | ((unsigned)v.w << 24);
            *(unsigned int*)(ws8 + rr * WSTRIDE + j * 4) = u;
        }
        __syncthreads();

        float s[R], s8[R];
        #pragma unroll
        for (int r = 0; r < R; ++r) {
            float sv = (sub == 0) ? sc[r].x : sc[r].y;   // sub is constant
            s[r]  = sv;
            s8[r] = -8.0f * sv;   // exact
        }

        for (int k4 = 0; k4 < WSUB / 4; ++k4) {      // 8 (rolled)
            unsigned int q[R];
            #pragma unroll
            for (int r = 0; r < R; ++r)
                q[r] = *(const unsigned int*)(ws8 + (tid + r * THREADS) * WSTRIDE + k4 * 4);

            #pragma unroll
            for (int kk = 0; kk < 4; ++kk) {
                const float4* xp = (const float4*)&xs[sub * WSUB + k4 * 4 + kk][0];
                float4 x0 = xp[0], x1 = xp[1], x2 = xp[2], x3 = xp[3];
                #pragma unroll
                for (int r = 0; r < R; ++r) {
                    // (q - 8) * s with a single rounding; byte extract is
                    // kk-constant -> v_cvt_f32_ubyte{kk}
                    float wv = fmaf((float)((q[r] >> (8 * kk)) & 0xffu), s[r], s8[r]);
                    acc[r][0]  = fmaf(wv, x0.x, acc[r][0]);
                    acc[r][1]  = fmaf(wv, x0.y, acc[r][1]);
                    acc[r][2]  = fmaf(wv, x0.z, acc[r][2]);
                    acc[r][3]  = fmaf(wv, x0.w, acc[r][3]);
                    acc[r][4]  = fmaf(wv, x1.x, acc[r][4]);
                    acc[r][5]  = fmaf(wv, x1.y, acc[r][5]);
                    acc[r][6]  = fmaf(wv, x1.z, acc[r][6]);
                    acc[r][7]  = fmaf(wv, x1.w, acc[r][7]);
                    acc[r][8]  = fmaf(wv, x2.x, acc[r][8]);
                    acc[r][9]  = fmaf(wv, x2.y, acc[r][9]);
                    acc[r][10] = fmaf(wv, x2.z, acc[r][10]);
                    acc[r][11] = fmaf(wv, x2.w, acc[r][11]);
                    acc[r][12] = fmaf(wv, x3.x, acc[r][12]);
                    acc[r][13] = fmaf(wv, x3.y, acc[r][13]);
                    acc[r][14] = fmaf(wv, x3.z, acc[r][14]);
                    acc[r][15] = fmaf(wv, x3.w, acc[r][15]);
                }
            }
        }
    }

    // ---- epilogue: bias (split 0 only) + atomic combine across splits ----
    const bool add_b = (blockIdx.y == 0);
    #pragma unroll
    for (int r = 0; r < R; ++r) {
        int rg = row0 + tid + r * THREADS;
        if (rg < OUT) {
            float b = add_b ? bias[rg] : 0.0f;
            #pragma unroll
            for (int t = 0; t < T; ++t)
                atomicAdd(out + t * OUT + rg, acc[r][t] + b);
        }
    }
}

extern "C" void kernel_launch(void* const* d_in, const int* in_sizes, int n_in,
                              void* d_out, int out_size, void* d_ws, size_t ws_size,
                              hipStream_t stream) {
    const float* x       = (const float*)d_in[0];
    const int*   w_q     = (const int*)d_in[1];
    const float* w_scale = (const float*)d_in[2];
    const float* bias    = (const float*)d_in[3];
    float*       out     = (float*)d_out;

    // Zero the (0xAA-poisoned) output; captured as a graph memset node.
    hipMemsetAsync(d_out, 0, (size_t)out_size * sizeof(float), stream);

    dim3 grid((OUT + ROWSB - 1) / ROWSB, IN / CK);   // 22 x 64 = 1408 blocks
    qlinear_r2k64o<<<grid, THREADS, 0, stream>>>(x, w_q, w_scale, bias, out);
}

// Round 4
// 282.843 us; speedup vs baseline: 2.3502x; 2.3502x over previous
//
#include <hip/hip_runtime.h>

// Q4_0 quantized linear: out[16, 11008] = x[16, 4096] @ ((w_q-8)*w_scale).T + bias
// All fp32; w_q holds int32 nibble values in [0,16).
//
// R=4 row-blocked split-K GEMV, CK=64 (64 k-splits).
// History:
//  R0 (R=4, CK=128, 352 blocks): 110 us kernel, VGPR 84, occ 15% --
//     latency-bound at 1.375 blocks/CU. The ONLY clean compile so far.
//  R1 (explicit 16x int4 reg-prefetch): VGPR 256 + spill storm, 1540 us.
//  R2 (R=2, CK=64, no hint): compiler used the headroom freed by R=2
//     (acc 64->32 regs) to build its OWN cross-sub prefetch -> 256 VGPR,
//     2 blocks/CU, 168 us.
//  R3 (R=2 + launch_bounds(256,4)): allocator quantized DOWN to 64 VGPR
//     and spilled acc (FETCH/WRITE ~700 MB symmetric, VALUBusy 3.5%), 490 us.
//  R4 (this): back to the R0 body verbatim -- R=4's acc[4][16] (64 regs of
//     live state) is the guard rail that stops the allocator inventing a
//     pipeline. Only change: CK 128->64 doubles the grid to 704 blocks =
//     2.75 blocks/CU (LDS 41 KiB caps at 3). launch_bounds(256,3) caps
//     VGPR at ~168 (needed: 84 -- far from both the 256 blowup and the
//     spill cliff). Atomic combine doubles to 45 MB writes (~2 us).
// Structure: w packed to BYTES in LDS (row stride 36 B -> 2-way bank
// aliasing = free), x chunk staged transposed for broadcast float4 reads,
// fp32 atomicAdd split-K combine, bias added by split 0.

constexpr int T       = 16;
constexpr int IN      = 4096;
constexpr int OUT     = 11008;
constexpr int NSCALE  = IN / 32;        // 128 scales per row
constexpr int THREADS = 256;
constexpr int R       = 4;              // rows per thread
constexpr int ROWSB   = THREADS * R;    // 1024 rows per block
constexpr int CK      = 64;             // k per block (split-K chunk)
constexpr int WSUB    = 32;             // k per stage (== Q4_0 block size)
constexpr int NSUB    = CK / WSUB;      // 2
constexpr int WSTRIDE = 36;             // ws8 row stride bytes (32 + 4 pad -> 9 words)
constexpr int XPAD    = 20;             // xs row stride floats (80 B, 16B-aligned)

__global__ __launch_bounds__(THREADS, 3) void qlinear_r4k64(
    const float* __restrict__ x,        // [T, IN]
    const int*   __restrict__ w_q,      // [OUT, IN]
    const float* __restrict__ w_scale,  // [OUT, NSCALE]
    const float* __restrict__ bias,     // [OUT]
    float* __restrict__ out)            // [T, OUT] (pre-zeroed)
{
    __shared__ __align__(16) float         xs[CK][XPAD];           // 5.0 KiB
    __shared__ __align__(16) unsigned char ws8[ROWSB * WSTRIDE];   // 36 KiB

    const int tid  = threadIdx.x;
    const int row0 = blockIdx.x * ROWSB;
    const int k0   = blockIdx.y * CK;

    // ---- stage x chunk transposed: xs[k][t] = x[t][k0+k] (coalesced) ----
    #pragma unroll
    for (int it = 0; it < CK * T / THREADS; ++it) {  // 4
        int idx = it * THREADS + tid;
        int t   = idx >> 6;          // idx / CK
        int k   = idx & (CK - 1);
        xs[k][t] = x[t * IN + k0 + k];
    }

    // ---- per-row scales for the 2 sub-blocks of this k-chunk ----
    float2 sc[R];
    #pragma unroll
    for (int r = 0; r < R; ++r) {
        int rg = min(row0 + tid + r * THREADS, OUT - 1);
        sc[r] = *(const float2*)(w_scale + rg * NSCALE + (k0 >> 5));
    }

    float acc[R][T];
    #pragma unroll
    for (int r = 0; r < R; ++r)
        #pragma unroll
        for (int t = 0; t < T; ++t) acc[r][t] = 0.0f;

    #pragma unroll
    for (int sub = 0; sub < NSUB; ++sub) {           // 2
        __syncthreads();   // protect ws8 reuse (covers xs on first trip)

        // ---- stage w tile: 1024 rows x 32 ints -> packed bytes in LDS ----
        // flat int4 id f: row rr = f/8, j = f%8; lanes 0..7 read 128
        // contiguous bytes of one row (fully coalesced dwordx4 loads).
        #pragma unroll 4
        for (int it = 0; it < (ROWSB * WSUB / 4) / THREADS; ++it) {  // 32
            int f  = it * THREADS + tid;
            int rr = f >> 3;
            int j  = f & 7;
            int rg = min(row0 + rr, OUT - 1);
            const int4 v = *(const int4*)(w_q + rg * IN + k0 + sub * WSUB + j * 4);
            unsigned int u = (unsigned)v.x | ((unsigned)v.y << 8) |
                             ((unsigned)v.z << 16) | ((unsigned)v.w << 24);
            *(unsigned int*)(ws8 + rr * WSTRIDE + j * 4) = u;
        }
        __syncthreads();

        float s[R], s8[R];
        #pragma unroll
        for (int r = 0; r < R; ++r) {
            float sv = (sub == 0) ? sc[r].x : sc[r].y;   // sub is constant
            s[r]  = sv;
            s8[r] = -8.0f * sv;   // exact
        }

        for (int k4 = 0; k4 < WSUB / 4; ++k4) {      // 8 (rolled)
            unsigned int q[R];
            #pragma unroll
            for (int r = 0; r < R; ++r)
                q[r] = *(const unsigned int*)(ws8 + (tid + r * THREADS) * WSTRIDE + k4 * 4);

            #pragma unroll
            for (int kk = 0; kk < 4; ++kk) {
                const float4* xp = (const float4*)&xs[sub * WSUB + k4 * 4 + kk][0];
                float4 x0 = xp[0], x1 = xp[1], x2 = xp[2], x3 = xp[3];
                #pragma unroll
                for (int r = 0; r < R; ++r) {
                    // (q - 8) * s with a single rounding; byte extract is
                    // kk-constant -> v_cvt_f32_ubyte{kk}
                    float wv = fmaf((float)((q[r] >> (8 * kk)) & 0xffu), s[r], s8[r]);
                    acc[r][0]  = fmaf(wv, x0.x, acc[r][0]);
                    acc[r][1]  = fmaf(wv, x0.y, acc[r][1]);
                    acc[r][2]  = fmaf(wv, x0.z, acc[r][2]);
                    acc[r][3]  = fmaf(wv, x0.w, acc[r][3]);
                    acc[r][4]  = fmaf(wv, x1.x, acc[r][4]);
                    acc[r][5]  = fmaf(wv, x1.y, acc[r][5]);
                    acc[r][6]  = fmaf(wv, x1.z, acc[r][6]);
                    acc[r][7]  = fmaf(wv, x1.w, acc[r][7]);
                    acc[r][8]  = fmaf(wv, x2.x, acc[r][8]);
                    acc[r][9]  = fmaf(wv, x2.y, acc[r][9]);
                    acc[r][10] = fmaf(wv, x2.z, acc[r][10]);
                    acc[r][11] = fmaf(wv, x2.w, acc[r][11]);
                    acc[r][12] = fmaf(wv, x3.x, acc[r][12]);
                    acc[r][13] = fmaf(wv, x3.y, acc[r][13]);
                    acc[r][14] = fmaf(wv, x3.z, acc[r][14]);
                    acc[r][15] = fmaf(wv, x3.w, acc[r][15]);
                }
            }
        }
    }

    // ---- epilogue: bias (split 0 only) + atomic combine across splits ----
    const bool add_b = (blockIdx.y == 0);
    #pragma unroll
    for (int r = 0; r < R; ++r) {
        int rg = row0 + tid + r * THREADS;
        if (rg < OUT) {
            float b = add_b ? bias[rg] : 0.0f;
            #pragma unroll
            for (int t = 0; t < T; ++t)
                atomicAdd(out + t * OUT + rg, acc[r][t] + b);
        }
    }
}

extern "C" void kernel_launch(void* const* d_in, const int* in_sizes, int n_in,
                              void* d_out, int out_size, void* d_ws, size_t ws_size,
                              hipStream_t stream) {
    const float* x       = (const float*)d_in[0];
    const int*   w_q     = (const int*)d_in[1];
    const float* w_scale = (const float*)d_in[2];
    const float* bias    = (const float*)d_in[3];
    float*       out     = (float*)d_out;

    // Zero the (0xAA-poisoned) output; captured as a graph memset node.
    hipMemsetAsync(d_out, 0, (size_t)out_size * sizeof(float), stream);

    dim3 grid((OUT + ROWSB - 1) / ROWSB, IN / CK);   // 11 x 64 = 704 blocks
    qlinear_r4k64<<<grid, THREADS, 0, stream>>>(x, w_q, w_scale, bias, out);
}